// Round 4
// baseline (289.619 us; speedup 1.0000x reference)
//
#include <hip/hip_runtime.h>

typedef __attribute__((ext_vector_type(8))) _Float16 half8;
typedef __attribute__((ext_vector_type(4))) float floatx4;

#define AS1 __attribute__((address_space(1)))
#define AS3 __attribute__((address_space(3)))

__device__ __forceinline__ void async_load16(const void* g, void* l) {
  __builtin_amdgcn_global_load_lds((AS1 void*)(unsigned long long)g,
                                   (AS3 void*)(unsigned long long)l, 16, 0, 0);
}

template <int N>
__device__ __forceinline__ void wait_vm() {
  static_assert(N >= 0 && N <= 12, "extend wait_vm");
  if constexpr (N == 0) asm volatile("s_waitcnt vmcnt(0)" ::: "memory");
  else if constexpr (N == 1) asm volatile("s_waitcnt vmcnt(1)" ::: "memory");
  else if constexpr (N == 2) asm volatile("s_waitcnt vmcnt(2)" ::: "memory");
  else if constexpr (N == 3) asm volatile("s_waitcnt vmcnt(3)" ::: "memory");
  else if constexpr (N == 4) asm volatile("s_waitcnt vmcnt(4)" ::: "memory");
  else if constexpr (N == 5) asm volatile("s_waitcnt vmcnt(5)" ::: "memory");
  else if constexpr (N == 6) asm volatile("s_waitcnt vmcnt(6)" ::: "memory");
  else if constexpr (N == 7) asm volatile("s_waitcnt vmcnt(7)" ::: "memory");
  else if constexpr (N == 8) asm volatile("s_waitcnt vmcnt(8)" ::: "memory");
  else if constexpr (N == 9) asm volatile("s_waitcnt vmcnt(9)" ::: "memory");
  else if constexpr (N == 10) asm volatile("s_waitcnt vmcnt(10)" ::: "memory");
  else if constexpr (N == 11) asm volatile("s_waitcnt vmcnt(11)" ::: "memory");
  else asm volatile("s_waitcnt vmcnt(12)" ::: "memory");
}

// ---------------- GroupNorm stats: one block per (b, g); region is contiguous 16*2048 floats
__global__ __launch_bounds__(256) void gn_stats(const float* __restrict__ x,
                                                float* __restrict__ stats) {
  const int bg = blockIdx.x;
  const float4* p4 = (const float4*)(x + (long long)bg * 32768);
  const int t = threadIdx.x;
  float s = 0.f, ss = 0.f;
  for (int i = t; i < 8192; i += 256) {
    float4 v = p4[i];
    s += v.x + v.y + v.z + v.w;
    ss += v.x * v.x + v.y * v.y + v.z * v.z + v.w * v.w;
  }
#pragma unroll
  for (int off = 32; off; off >>= 1) { s += __shfl_down(s, off); ss += __shfl_down(ss, off); }
  __shared__ float rs[4], rss[4];
  if ((t & 63) == 0) { rs[t >> 6] = s; rss[t >> 6] = ss; }
  __syncthreads();
  if (t == 0) {
    s = rs[0] + rs[1] + rs[2] + rs[3];
    ss = rss[0] + rss[1] + rss[2] + rss[3];
    float mean = s * (1.f / 32768.f);
    float var = ss * (1.f / 32768.f) - mean * mean;
    stats[bg] = mean;
    stats[256 + bg] = rsqrtf(var + 1e-5f);
  }
}

// ---------------- normalize + transpose: x[b,c,l] fp32 -> ht[b,l,c] fp16
__global__ __launch_bounds__(256) void gn_apply(const float* __restrict__ x,
                                                const float* __restrict__ stats,
                                                const float* __restrict__ gsc,
                                                const float* __restrict__ gbi,
                                                _Float16* __restrict__ ht) {
  __shared__ float tile[64][65];
  const int b = blockIdx.z, c0 = blockIdx.y * 64, l0 = blockIdx.x * 64;
  const int t = threadIdx.x, tr = t >> 6, tc = t & 63;
  const float* xb = x + ((long long)b * 512 + c0) * 2048 + l0;
#pragma unroll
  for (int p = 0; p < 16; ++p) {
    int row = tr + p * 4;
    tile[row][tc] = xb[(long long)row * 2048 + tc];
  }
  __syncthreads();
  const int c = c0 + tc;
  const int bg = b * 32 + (c >> 4);
  const float mean = stats[bg], rstd = stats[256 + bg];
  const float sc = gsc[c] * rstd;
  const float off = gbi[c] - mean * sc;
  _Float16* hb = ht + ((long long)b * 2048 + l0) * 512 + c0;
#pragma unroll
  for (int p = 0; p < 16; ++p) {
    int l = tr + p * 4;
    hb[(long long)l * 512 + tc] = (_Float16)(tile[tc][l] * sc + off);
  }
}

// ---------------- cast 4 weight matrices fp32 -> fp16, plus pack bq||bk into bqk (f32)
__global__ __launch_bounds__(256) void cast_w(const float* __restrict__ w0, const float* __restrict__ w1,
                                              const float* __restrict__ w2, const float* __restrict__ w3,
                                              const float* __restrict__ bq, const float* __restrict__ bk,
                                              _Float16* __restrict__ outw, float* __restrict__ bqk) {
  const long long i = (long long)blockIdx.x * 256 + threadIdx.x;
  if (blockIdx.x < 4096) {
    const int m = (int)(i >> 18);
    const int r = (int)(i & 262143);
    const float* w = (m == 0) ? w0 : (m == 1) ? w1 : (m == 2) ? w2 : w3;
    outw[i] = (_Float16)w[r];
  } else {
    const int j = (int)(i - 4096LL * 256);  // 0..1023
    bqk[j] = (j < 512) ? bq[j] : bk[j - 512];
  }
}

// ---------------- 8-wave 2-phase-per-K-tile GEMM: C[M,N] = alpha*A[M,K]*Bt[N,K]^T (+bias)(+resid)
// BMxBN tile, BK=64, double-buffered LDS, XOR-swizzled (conflict-free ds_read_b128).
// ONLY 2 BARRIERS PER K-TILE (was 8): 32-MFMA clusters; each wave's ds_read issue
// overlaps other waves' MFMA (no intervening barrier), so LDS and MFMA cycles no
// longer sum serially CU-wide.
//   phase A: barrier#1 -> read A0,B0,B1 -> issue all L DMA loads of kt+1
//            -> vmcnt(L)  [retires A1(kt), 2-phase flight] -> MFMA (0,0)+(0,1)
//   phase B: barrier#2 -> read A1 (reuses af regs) -> vmcnt(LA)
//            [retires A0,B0,B1(kt+1), 1-phase flight] -> MFMA (1,1)+(1,0)
// Invariant: outstanding = LA entering each tile (verified for LA=LB=2 and LA=1,LB=2,
// incl. kt=0 no-op waits and peeled last tile).
// Hazards: every ds_read block is pinned above a memory-clobber wait_vm before the
// next barrier; DMA overwrite of a buffer is >=1 barrier after the lgkm-guarded
// consumption of its last reads; bf0/bf1 stay live across barrier#2 (not re-read).
// Grid: x = batch (XCD-local), y = m-tile, z = n-tile.
template <int BM, int BN, int BIAS_MODE /*0 none,1 over n,2 over m*/, int OUT_TYPE /*0 f32,1 f16*/, bool RESIDUAL>
__global__ __launch_bounds__(512, 2) void gemm2p(
    const _Float16* __restrict__ A, long long sA, int lda,
    const _Float16* __restrict__ Bt, long long sB, int ldb,
    void* __restrict__ Cv, long long sC, int ldc,
    const float* __restrict__ bias,
    const float* __restrict__ resid, long long sR,
    float alpha, int K) {
  constexpr int ASZ = BM * 64, BSZ = BN * 64;  // halfs per K-tile
  constexpr int BUF = ASZ + BSZ;
  constexpr int RWA = BM / 16, RWB = BN / 16;  // staged rows per wave per half-tile
  constexpr int LA = RWA / 8, LB = RWB / 8;    // global_load_lds per wave per half-tile
  constexpr int L = 2 * LA + 2 * LB;           // loads per wave per K-tile
  constexpr int NMI = BM / 64, NNJ = BN / 128; // frags per quadrant (per wave)
  __shared__ __align__(16) _Float16 ls[2 * BUF];

  const int tid = threadIdx.x;
  const int wave = tid >> 6, lane = tid & 63;
  const int wr = wave >> 2, wc = wave & 3;  // 2 x 4 wave grid
  const int fm = lane & 15, q = lane >> 4;
  const int bz = blockIdx.x;
  const int m0 = blockIdx.y * BM, n0 = blockIdx.z * BN;
  A += (long long)bz * sA;
  Bt += (long long)bz * sB;

  // staging geometry: per instruction a wave writes 8 rows x 128B linear LDS;
  // swizzle done by pre-swizzling the global column each lane fetches.
  const int srow = lane >> 3;
  const int schunk = ((lane & 7) ^ (srow & 7)) * 8;
  const _Float16* pA0 = A + (long long)(m0 + RWA * wave + srow) * lda + schunk;
  const _Float16* pA1 = pA0 + (long long)(BM / 2) * lda;
  const _Float16* pB0 = Bt + (long long)(n0 + RWB * wave + srow) * ldb + schunk;
  const _Float16* pB1 = pB0 + (long long)(BN / 2) * ldb;
  const int dA0 = RWA * wave * 64;        // halfs, within A region
  const int dB0 = ASZ + RWB * wave * 64;  // halfs, within B region

  // read geometry: global chunk ca of row r lives at LDS chunk ca^(r&7); r&7 == fm&7 here.
  const int c0 = (q ^ (fm & 7)) * 8;        // kk=0
  const int c1 = ((q + 4) ^ (fm & 7)) * 8;  // kk=1
  const int arow = wr * (BM / 4) + fm;
  const int brow = wc * (BN / 8) + fm;

  floatx4 acc[2][2][NMI][NNJ] = {};
  half8 af[NMI][2], bf0[NNJ][2], bf1[NNJ][2];

  const int NT = K >> 6;

  // prologue: stage all four half-tiles of K-tile 0 into buf0 and drain
  // (loop's barrier#1 publishes before first read)
  {
    _Float16* st = ls;
#pragma unroll
    for (int s = 0; s < LA; ++s) async_load16(pA0 + (long long)(8 * s) * lda, st + dA0 + s * 512);
#pragma unroll
    for (int s = 0; s < LB; ++s) async_load16(pB0 + (long long)(8 * s) * ldb, st + dB0 + s * 512);
#pragma unroll
    for (int s = 0; s < LB; ++s) async_load16(pB1 + (long long)(8 * s) * ldb, st + dB0 + BSZ / 2 + s * 512);
#pragma unroll
    for (int s = 0; s < LA; ++s) async_load16(pA1 + (long long)(8 * s) * lda, st + dA0 + ASZ / 2 + s * 512);
    pA0 += 64; pA1 += 64; pB0 += 64; pB1 += 64;
    wait_vm<0>();
  }

#define G8_READ_A(MH)                                                      \
  _Pragma("unroll") for (int mi = 0; mi < NMI; ++mi) {                     \
    const int r_ = (MH) * (BM / 2) + arow + 16 * mi;                       \
    af[mi][0] = *(const half8*)&cb[r_ * 64 + c0];                          \
    af[mi][1] = *(const half8*)&cb[r_ * 64 + c1];                          \
  }
#define G8_READ_B(NH, BF)                                                  \
  _Pragma("unroll") for (int nj = 0; nj < NNJ; ++nj) {                     \
    const int r_ = ASZ + ((NH) * (BN / 2) + brow + 16 * nj) * 64;          \
    BF[nj][0] = *(const half8*)&cb[r_ + c0];                               \
    BF[nj][1] = *(const half8*)&cb[r_ + c1];                               \
  }
#define G8_MFMA(MH, NH, BF)                                                \
  __builtin_amdgcn_s_setprio(1);                                           \
  _Pragma("unroll") for (int mi = 0; mi < NMI; ++mi)                       \
  _Pragma("unroll") for (int nj = 0; nj < NNJ; ++nj) {                     \
    acc[MH][NH][mi][nj] = __builtin_amdgcn_mfma_f32_16x16x32_f16(          \
        af[mi][0], BF[nj][0], acc[MH][NH][mi][nj], 0, 0, 0);               \
    acc[MH][NH][mi][nj] = __builtin_amdgcn_mfma_f32_16x16x32_f16(          \
        af[mi][1], BF[nj][1], acc[MH][NH][mi][nj], 0, 0, 0);               \
  }                                                                        \
  __builtin_amdgcn_s_setprio(0);
#define G8_STAGE_A(PTR, OFF)                                               \
  _Pragma("unroll") for (int s = 0; s < LA; ++s)                           \
    async_load16(PTR + (long long)(8 * s) * lda, st + dA0 + (OFF) + s * 512);
#define G8_STAGE_B(PTR, OFF)                                               \
  _Pragma("unroll") for (int s = 0; s < LB; ++s)                           \
    async_load16(PTR + (long long)(8 * s) * ldb, st + dB0 + (OFF) + s * 512);

  for (int kt = 0; kt < NT - 1; ++kt) {
    const _Float16* cb = ls + (kt & 1) * BUF;
    _Float16* st = ls + ((kt + 1) & 1) * BUF;
    // ---- phase A
    __builtin_amdgcn_s_barrier();  // publishes A0,B0,B1(kt); fences A1(kt-1) use vs DMA below
    G8_READ_A(0)
    G8_READ_B(0, bf0)
    G8_READ_B(1, bf1)
    G8_STAGE_A(pA0, 0)
    G8_STAGE_B(pB0, 0)
    G8_STAGE_B(pB1, BSZ / 2)
    G8_STAGE_A(pA1, ASZ / 2)
    pA0 += 64; pA1 += 64; pB0 += 64; pB1 += 64;
    wait_vm<L>();  // retires A1(kt)
    G8_MFMA(0, 0, bf0)
    G8_MFMA(0, 1, bf1)
    // ---- phase B
    __builtin_amdgcn_s_barrier();  // publishes A1(kt)
    G8_READ_A(1)
    wait_vm<LA>();  // retires A0,B0,B1(kt+1)
    G8_MFMA(1, 1, bf1)
    G8_MFMA(1, 0, bf0)
  }
  // last K-tile: no staging
  {
    const _Float16* cb = ls + ((NT - 1) & 1) * BUF;
    __builtin_amdgcn_s_barrier();
    G8_READ_A(0)
    G8_READ_B(0, bf0)
    G8_READ_B(1, bf1)
    wait_vm<0>();  // retire A1(last)
    G8_MFMA(0, 0, bf0)
    G8_MFMA(0, 1, bf1)
    __builtin_amdgcn_s_barrier();
    G8_READ_A(1)
    G8_MFMA(1, 1, bf1)
    G8_MFMA(1, 0, bf0)
  }

#undef G8_READ_A
#undef G8_READ_B
#undef G8_MFMA
#undef G8_STAGE_A
#undef G8_STAGE_B

  // epilogue: C/D layout col=lane&15, row=(lane>>4)*4+reg  [verified m89/m91]
#pragma unroll
  for (int mh = 0; mh < 2; ++mh)
#pragma unroll
    for (int nh = 0; nh < 2; ++nh)
#pragma unroll
      for (int mi = 0; mi < NMI; ++mi)
#pragma unroll
        for (int nj = 0; nj < NNJ; ++nj) {
          const int rr0 = m0 + mh * (BM / 2) + wr * (BM / 4) + 16 * mi + 4 * q;
          const int cc = n0 + nh * (BN / 2) + wc * (BN / 8) + 16 * nj + fm;
#pragma unroll
          for (int t = 0; t < 4; ++t) {
            const int rr = rr0 + t;
            float v = acc[mh][nh][mi][nj][t] * alpha;
            if (BIAS_MODE == 1) v += bias[cc];
            if (BIAS_MODE == 2) v += bias[rr];
            if (RESIDUAL) v += resid[(long long)bz * sR + (long long)rr * ldc + cc];
            const long long off = (long long)bz * sC + (long long)rr * ldc + cc;
            if (OUT_TYPE == 0) ((float*)Cv)[off] = v;
            else ((_Float16*)Cv)[off] = (_Float16)v;
          }
        }
}

// ---------------- row softmax on S (fp16, in place). One block per row of 2048.
__global__ __launch_bounds__(256) void softmax_inplace(_Float16* __restrict__ S) {
  const long long row = (long long)blockIdx.y * 2048 + blockIdx.x;
  _Float16* p = S + row * 2048;
  const int t = threadIdx.x;
  union U { float4 f; _Float16 h[8]; } u;
  u.f = ((const float4*)p)[t];  // all reads complete before first barrier
  float v[8];
  float mx = -3e38f;
#pragma unroll
  for (int i = 0; i < 8; ++i) { v[i] = (float)u.h[i]; mx = fmaxf(mx, v[i]); }
#pragma unroll
  for (int off = 32; off; off >>= 1) mx = fmaxf(mx, __shfl_down(mx, off));
  __shared__ float red[4];
  if ((t & 63) == 0) red[t >> 6] = mx;
  __syncthreads();
  mx = fmaxf(fmaxf(red[0], red[1]), fmaxf(red[2], red[3]));
  float s = 0.f;
#pragma unroll
  for (int i = 0; i < 8; ++i) { v[i] = __expf(v[i] - mx); s += v[i]; }
#pragma unroll
  for (int off = 32; off; off >>= 1) s += __shfl_down(s, off);
  __syncthreads();
  if ((t & 63) == 0) red[t >> 6] = s;
  __syncthreads();
  s = red[0] + red[1] + red[2] + red[3];
  const float inv = 1.f / s;
#pragma unroll
  for (int i = 0; i < 8; ++i) u.h[i] = (_Float16)(v[i] * inv);
  ((float4*)p)[t] = u.f;  // writes only after final barrier
}

extern "C" void kernel_launch(void* const* d_in, const int* in_sizes, int n_in,
                              void* d_out, int out_size, void* d_ws, size_t ws_size,
                              hipStream_t stream) {
  const float* x = (const float*)d_in[0];
  const float* gsc = (const float*)d_in[1];
  const float* gbi = (const float*)d_in[2];
  const float* wq = (const float*)d_in[3];
  const float* bq = (const float*)d_in[4];
  const float* wk = (const float*)d_in[5];
  const float* bk = (const float*)d_in[6];
  const float* wv = (const float*)d_in[7];
  const float* bv = (const float*)d_in[8];
  const float* wo = (const float*)d_in[9];
  const float* bo = (const float*)d_in[10];
  float* out = (float*)d_out;

  // workspace layout (~130 MB total)
  char* ws = (char*)d_ws;
  float* stats = (float*)ws;                 // 512 f32 @ 0
  float* bqk = (float*)(ws + 2048);          // 1024 f32 @ 2 KB
  _Float16* wbf = (_Float16*)(ws + 8192);    // 4 * 512*512 f16 (wq,wk,wv,wo stacked)
  _Float16* ht = wbf + 4 * 262144;           // [b,l,c] f16, 16 MB
  const long long EB = 8LL * 2048 * 512;
  _Float16* qk = ht + EB;       // [b,l,1024] f16 (q||k), 32 MB
  _Float16* vm = qk + 2 * EB;   // [b,c,l] f16, 16 MB
  _Float16* Sb = vm + EB;       // [b,l,l] f16, 64 MB (softmax in place)
  _Float16* at = ht;            // attention output aliases ht (ht dead after V-proj)

  gn_stats<<<256, 256, 0, stream>>>(x, stats);
  gn_apply<<<dim3(32, 8, 8), 256, 0, stream>>>(x, stats, gsc, gbi, ht);
  cast_w<<<4100, 256, 0, stream>>>(wq, wk, wv, wo, bq, bk, wbf, bqk);

  const float scale = 0.044194173824159216f;  // 512^-0.5
  // QK fused: [l, 0:1024] = ht[l,c] . (wq||wk)[o,c]^T + bqk[o]
  gemm2p<256, 256, 1, 1, false><<<dim3(8, 8, 4), 512, 0, stream>>>(
      ht, 1048576LL, 512, wbf, 0LL, 512, qk, 2097152LL, 1024, bqk, nullptr, 0LL, 1.f, 512);
  // V: [o,l] = Wv[o,c] . ht[l,c]^T + bv[o]
  gemm2p<128, 256, 2, 1, false><<<dim3(8, 4, 8), 512, 0, stream>>>(
      wbf + 2 * 262144, 0LL, 512, ht, 1048576LL, 512, vm, 1048576LL, 2048, bv, nullptr, 0LL, 1.f, 512);
  // S: [i,j] = scale * q[i,o] . k[j,o]^T
  gemm2p<256, 256, 0, 1, false><<<dim3(8, 8, 8), 512, 0, stream>>>(
      qk, 2097152LL, 1024, qk + 512, 2097152LL, 1024, Sb, 4194304LL, 2048, nullptr, nullptr, 0LL, scale, 512);
  softmax_inplace<<<dim3(2048, 8), 256, 0, stream>>>(Sb);
  // A: [i,c] = P[i,j] . vm[c,j]^T
  gemm2p<128, 256, 0, 1, false><<<dim3(8, 16, 2), 512, 0, stream>>>(
      Sb, 4194304LL, 2048, vm, 1048576LL, 2048, at, 1048576LL, 512, nullptr, nullptr, 0LL, 1.f, 2048);
  // Out: [o,l] = Wo[o,c] . a[l,c]^T + bo[o] + x[b,o,l]
  gemm2p<128, 256, 2, 0, true><<<dim3(8, 4, 8), 512, 0, stream>>>(
      wbf + 3 * 262144, 0LL, 512, at, 1048576LL, 512, out, 1048576LL, 2048, bo, x, 1048576LL, 1.f, 512);
}

// Round 5
// 277.184 us; speedup vs baseline: 1.0449x; 1.0449x over previous
//
#include <hip/hip_runtime.h>

typedef __attribute__((ext_vector_type(8))) _Float16 half8;
typedef __attribute__((ext_vector_type(4))) float floatx4;

#define AS1 __attribute__((address_space(1)))
#define AS3 __attribute__((address_space(3)))

__device__ __forceinline__ void async_load16(const void* g, void* l) {
  __builtin_amdgcn_global_load_lds((AS1 void*)(unsigned long long)g,
                                   (AS3 void*)(unsigned long long)l, 16, 0, 0);
}

template <int N>
__device__ __forceinline__ void wait_vm() {
  static_assert(N >= 0 && N <= 12, "extend wait_vm");
  if constexpr (N == 0) asm volatile("s_waitcnt vmcnt(0)" ::: "memory");
  else if constexpr (N == 1) asm volatile("s_waitcnt vmcnt(1)" ::: "memory");
  else if constexpr (N == 2) asm volatile("s_waitcnt vmcnt(2)" ::: "memory");
  else if constexpr (N == 3) asm volatile("s_waitcnt vmcnt(3)" ::: "memory");
  else if constexpr (N == 4) asm volatile("s_waitcnt vmcnt(4)" ::: "memory");
  else if constexpr (N == 5) asm volatile("s_waitcnt vmcnt(5)" ::: "memory");
  else if constexpr (N == 6) asm volatile("s_waitcnt vmcnt(6)" ::: "memory");
  else if constexpr (N == 7) asm volatile("s_waitcnt vmcnt(7)" ::: "memory");
  else if constexpr (N == 8) asm volatile("s_waitcnt vmcnt(8)" ::: "memory");
  else if constexpr (N == 9) asm volatile("s_waitcnt vmcnt(9)" ::: "memory");
  else if constexpr (N == 10) asm volatile("s_waitcnt vmcnt(10)" ::: "memory");
  else if constexpr (N == 11) asm volatile("s_waitcnt vmcnt(11)" ::: "memory");
  else asm volatile("s_waitcnt vmcnt(12)" ::: "memory");
}

// ---------------- GroupNorm stats: one block per (b, g); region is contiguous 16*2048 floats
__global__ __launch_bounds__(256) void gn_stats(const float* __restrict__ x,
                                                float* __restrict__ stats) {
  const int bg = blockIdx.x;
  const float4* p4 = (const float4*)(x + (long long)bg * 32768);
  const int t = threadIdx.x;
  float s = 0.f, ss = 0.f;
  for (int i = t; i < 8192; i += 256) {
    float4 v = p4[i];
    s += v.x + v.y + v.z + v.w;
    ss += v.x * v.x + v.y * v.y + v.z * v.z + v.w * v.w;
  }
#pragma unroll
  for (int off = 32; off; off >>= 1) { s += __shfl_down(s, off); ss += __shfl_down(ss, off); }
  __shared__ float rs[4], rss[4];
  if ((t & 63) == 0) { rs[t >> 6] = s; rss[t >> 6] = ss; }
  __syncthreads();
  if (t == 0) {
    s = rs[0] + rs[1] + rs[2] + rs[3];
    ss = rss[0] + rss[1] + rss[2] + rss[3];
    float mean = s * (1.f / 32768.f);
    float var = ss * (1.f / 32768.f) - mean * mean;
    stats[bg] = mean;
    stats[256 + bg] = rsqrtf(var + 1e-5f);
  }
}

// ---------------- normalize + transpose: x[b,c,l] fp32 -> ht[b,l,c] fp16
__global__ __launch_bounds__(256) void gn_apply(const float* __restrict__ x,
                                                const float* __restrict__ stats,
                                                const float* __restrict__ gsc,
                                                const float* __restrict__ gbi,
                                                _Float16* __restrict__ ht) {
  __shared__ float tile[64][65];
  const int b = blockIdx.z, c0 = blockIdx.y * 64, l0 = blockIdx.x * 64;
  const int t = threadIdx.x, tr = t >> 6, tc = t & 63;
  const float* xb = x + ((long long)b * 512 + c0) * 2048 + l0;
#pragma unroll
  for (int p = 0; p < 16; ++p) {
    int row = tr + p * 4;
    tile[row][tc] = xb[(long long)row * 2048 + tc];
  }
  __syncthreads();
  const int c = c0 + tc;
  const int bg = b * 32 + (c >> 4);
  const float mean = stats[bg], rstd = stats[256 + bg];
  const float sc = gsc[c] * rstd;
  const float off = gbi[c] - mean * sc;
  _Float16* hb = ht + ((long long)b * 2048 + l0) * 512 + c0;
#pragma unroll
  for (int p = 0; p < 16; ++p) {
    int l = tr + p * 4;
    hb[(long long)l * 512 + tc] = (_Float16)(tile[tc][l] * sc + off);
  }
}

// ---------------- cast 4 weight matrices fp32 -> fp16, plus pack bq||bk into bqk (f32)
__global__ __launch_bounds__(256) void cast_w(const float* __restrict__ w0, const float* __restrict__ w1,
                                              const float* __restrict__ w2, const float* __restrict__ w3,
                                              const float* __restrict__ bq, const float* __restrict__ bk,
                                              _Float16* __restrict__ outw, float* __restrict__ bqk) {
  const long long i = (long long)blockIdx.x * 256 + threadIdx.x;
  if (blockIdx.x < 4096) {
    const int m = (int)(i >> 18);
    const int r = (int)(i & 262143);
    const float* w = (m == 0) ? w0 : (m == 1) ? w1 : (m == 2) ? w2 : w3;
    outw[i] = (_Float16)w[r];
  } else {
    const int j = (int)(i - 4096LL * 256);  // 0..1023
    bqk[j] = (j < 512) ? bq[j] : bk[j - 512];
  }
}

// ---------------- 8-wave 2-phase-per-K-tile GEMM (R4 structure, best measured).
// kk-outer MFMA order: dependent same-acc MFMAs separated by 7 independents.
template <int BM, int BN, int BIAS_MODE /*0 none,1 over n,2 over m*/, int OUT_TYPE /*0 f32,1 f16*/, bool RESIDUAL>
__global__ __launch_bounds__(512, 2) void gemm2p(
    const _Float16* __restrict__ A, long long sA, int lda,
    const _Float16* __restrict__ Bt, long long sB, int ldb,
    void* __restrict__ Cv, long long sC, int ldc,
    const float* __restrict__ bias,
    const float* __restrict__ resid, long long sR,
    float alpha, int K) {
  constexpr int ASZ = BM * 64, BSZ = BN * 64;  // halfs per K-tile
  constexpr int BUF = ASZ + BSZ;
  constexpr int RWA = BM / 16, RWB = BN / 16;  // staged rows per wave per half-tile
  constexpr int LA = RWA / 8, LB = RWB / 8;    // global_load_lds per wave per half-tile
  constexpr int L = 2 * LA + 2 * LB;           // loads per wave per K-tile
  constexpr int NMI = BM / 64, NNJ = BN / 128; // frags per quadrant (per wave)
  __shared__ __align__(16) _Float16 ls[2 * BUF];

  const int tid = threadIdx.x;
  const int wave = tid >> 6, lane = tid & 63;
  const int wr = wave >> 2, wc = wave & 3;  // 2 x 4 wave grid
  const int fm = lane & 15, q = lane >> 4;
  const int bz = blockIdx.x;
  const int m0 = blockIdx.y * BM, n0 = blockIdx.z * BN;
  A += (long long)bz * sA;
  Bt += (long long)bz * sB;

  const int srow = lane >> 3;
  const int schunk = ((lane & 7) ^ (srow & 7)) * 8;
  const _Float16* pA0 = A + (long long)(m0 + RWA * wave + srow) * lda + schunk;
  const _Float16* pA1 = pA0 + (long long)(BM / 2) * lda;
  const _Float16* pB0 = Bt + (long long)(n0 + RWB * wave + srow) * ldb + schunk;
  const _Float16* pB1 = pB0 + (long long)(BN / 2) * ldb;
  const int dA0 = RWA * wave * 64;        // halfs, within A region
  const int dB0 = ASZ + RWB * wave * 64;  // halfs, within B region

  const int c0 = (q ^ (fm & 7)) * 8;        // kk=0
  const int c1 = ((q + 4) ^ (fm & 7)) * 8;  // kk=1
  const int arow = wr * (BM / 4) + fm;
  const int brow = wc * (BN / 8) + fm;

  floatx4 acc[2][2][NMI][NNJ] = {};
  half8 af[NMI][2], bf0[NNJ][2], bf1[NNJ][2];

  const int NT = K >> 6;

  {
    _Float16* st = ls;
#pragma unroll
    for (int s = 0; s < LA; ++s) async_load16(pA0 + (long long)(8 * s) * lda, st + dA0 + s * 512);
#pragma unroll
    for (int s = 0; s < LB; ++s) async_load16(pB0 + (long long)(8 * s) * ldb, st + dB0 + s * 512);
#pragma unroll
    for (int s = 0; s < LB; ++s) async_load16(pB1 + (long long)(8 * s) * ldb, st + dB0 + BSZ / 2 + s * 512);
#pragma unroll
    for (int s = 0; s < LA; ++s) async_load16(pA1 + (long long)(8 * s) * lda, st + dA0 + ASZ / 2 + s * 512);
    pA0 += 64; pA1 += 64; pB0 += 64; pB1 += 64;
    wait_vm<0>();
  }

#define G8_READ_A(MH)                                                      \
  _Pragma("unroll") for (int mi = 0; mi < NMI; ++mi) {                     \
    const int r_ = (MH) * (BM / 2) + arow + 16 * mi;                       \
    af[mi][0] = *(const half8*)&cb[r_ * 64 + c0];                          \
    af[mi][1] = *(const half8*)&cb[r_ * 64 + c1];                          \
  }
#define G8_READ_B(NH, BF)                                                  \
  _Pragma("unroll") for (int nj = 0; nj < NNJ; ++nj) {                     \
    const int r_ = ASZ + ((NH) * (BN / 2) + brow + 16 * nj) * 64;          \
    BF[nj][0] = *(const half8*)&cb[r_ + c0];                               \
    BF[nj][1] = *(const half8*)&cb[r_ + c1];                               \
  }
#define G8_MFMA(MH, NH, BF)                                                \
  __builtin_amdgcn_s_setprio(1);                                           \
  _Pragma("unroll") for (int kk = 0; kk < 2; ++kk)                         \
  _Pragma("unroll") for (int mi = 0; mi < NMI; ++mi)                       \
  _Pragma("unroll") for (int nj = 0; nj < NNJ; ++nj)                       \
    acc[MH][NH][mi][nj] = __builtin_amdgcn_mfma_f32_16x16x32_f16(          \
        af[mi][kk], BF[nj][kk], acc[MH][NH][mi][nj], 0, 0, 0);             \
  __builtin_amdgcn_s_setprio(0);
#define G8_STAGE_A(PTR, OFF)                                               \
  _Pragma("unroll") for (int s = 0; s < LA; ++s)                           \
    async_load16(PTR + (long long)(8 * s) * lda, st + dA0 + (OFF) + s * 512);
#define G8_STAGE_B(PTR, OFF)                                               \
  _Pragma("unroll") for (int s = 0; s < LB; ++s)                           \
    async_load16(PTR + (long long)(8 * s) * ldb, st + dB0 + (OFF) + s * 512);

  for (int kt = 0; kt < NT - 1; ++kt) {
    const _Float16* cb = ls + (kt & 1) * BUF;
    _Float16* st = ls + ((kt + 1) & 1) * BUF;
    // ---- phase A
    __builtin_amdgcn_s_barrier();  // publishes A0,B0,B1(kt)
    G8_READ_A(0)
    G8_READ_B(0, bf0)
    G8_READ_B(1, bf1)
    G8_STAGE_A(pA0, 0)
    G8_STAGE_B(pB0, 0)
    G8_STAGE_B(pB1, BSZ / 2)
    G8_STAGE_A(pA1, ASZ / 2)
    pA0 += 64; pA1 += 64; pB0 += 64; pB1 += 64;
    wait_vm<L>();  // retires A1(kt)
    G8_MFMA(0, 0, bf0)
    G8_MFMA(0, 1, bf1)
    // ---- phase B
    __builtin_amdgcn_s_barrier();  // publishes A1(kt)
    G8_READ_A(1)
    wait_vm<LA>();  // retires A0,B0,B1(kt+1)
    G8_MFMA(1, 1, bf1)
    G8_MFMA(1, 0, bf0)
  }
  // last K-tile: no staging
  {
    const _Float16* cb = ls + ((NT - 1) & 1) * BUF;
    __builtin_amdgcn_s_barrier();
    G8_READ_A(0)
    G8_READ_B(0, bf0)
    G8_READ_B(1, bf1)
    wait_vm<0>();
    G8_MFMA(0, 0, bf0)
    G8_MFMA(0, 1, bf1)
    __builtin_amdgcn_s_barrier();
    G8_READ_A(1)
    G8_MFMA(1, 1, bf1)
    G8_MFMA(1, 0, bf0)
  }

#undef G8_READ_A
#undef G8_READ_B
#undef G8_MFMA
#undef G8_STAGE_A
#undef G8_STAGE_B

  // epilogue: C/D layout col=lane&15, row=(lane>>4)*4+reg  [verified m89/m91]
#pragma unroll
  for (int mh = 0; mh < 2; ++mh)
#pragma unroll
    for (int nh = 0; nh < 2; ++nh)
#pragma unroll
      for (int mi = 0; mi < NMI; ++mi)
#pragma unroll
        for (int nj = 0; nj < NNJ; ++nj) {
          const int rr0 = m0 + mh * (BM / 2) + wr * (BM / 4) + 16 * mi + 4 * q;
          const int cc = n0 + nh * (BN / 2) + wc * (BN / 8) + 16 * nj + fm;
#pragma unroll
          for (int t = 0; t < 4; ++t) {
            const int rr = rr0 + t;
            float v = acc[mh][nh][mi][nj][t] * alpha;
            if (BIAS_MODE == 1) v += bias[cc];
            if (BIAS_MODE == 2) v += bias[rr];
            if (RESIDUAL) v += resid[(long long)bz * sR + (long long)rr * ldc + cc];
            const long long off = (long long)bz * sC + (long long)rr * ldc + cc;
            if (OUT_TYPE == 0) ((float*)Cv)[off] = v;
            else ((_Float16*)Cv)[off] = (_Float16)v;
          }
        }
}

// ---------------- row stats for softmax fusion: per row of S, write (max, 1/sum(exp(v-max))).
__global__ __launch_bounds__(256) void row_stats(const _Float16* __restrict__ S,
                                                 float2* __restrict__ rms) {
  const long long row = (long long)blockIdx.y * 2048 + blockIdx.x;
  const _Float16* p = S + row * 2048;
  const int t = threadIdx.x;
  union U { float4 f; _Float16 h[8]; } u;
  u.f = ((const float4*)p)[t];
  float v[8];
  float mx = -3e38f;
#pragma unroll
  for (int i = 0; i < 8; ++i) { v[i] = (float)u.h[i]; mx = fmaxf(mx, v[i]); }
#pragma unroll
  for (int off = 32; off; off >>= 1) mx = fmaxf(mx, __shfl_down(mx, off));
  __shared__ float red[4];
  if ((t & 63) == 0) red[t >> 6] = mx;
  __syncthreads();
  mx = fmaxf(fmaxf(red[0], red[1]), fmaxf(red[2], red[3]));
  float s = 0.f;
#pragma unroll
  for (int i = 0; i < 8; ++i) s += __expf(v[i] - mx);
#pragma unroll
  for (int off = 32; off; off >>= 1) s += __shfl_down(s, off);
  __syncthreads();
  if ((t & 63) == 0) red[t >> 6] = s;
  __syncthreads();
  if (t == 0) {
    s = red[0] + red[1] + red[2] + red[3];
    rms[blockIdx.y * 2048 + blockIdx.x] = make_float2(mx, 1.f / s);
  }
}

// ---------------- fused softmax + PV GEMM: Out[i,c] = sum_j softmax(S)[i,j] * V[j,c]
// A-operand (P) is reg-staged: global half8 -> exp(v-m)*inv -> ds_write to the same
// swizzled LDS layout the DMA path would produce (lane reads swizzled global chunk,
// writes linear LDS at lane*16B). B (vm) uses DMA. Simple drain-style sync (per R0-R4
// evidence, schedule detail does not move perf at this shape).
// BM=128, BN=256, K=2048. Grid: x=batch, y=m-tile(16), z=n-tile(2).
__global__ __launch_bounds__(512, 2) void gemm_pv(
    const _Float16* __restrict__ S, const float2* __restrict__ rms,
    const _Float16* __restrict__ Vt, _Float16* __restrict__ Out) {
  constexpr int BM = 128, BN = 256;
  constexpr int ASZ = BM * 64, BSZ = BN * 64, BUF = ASZ + BSZ;
  constexpr int LB = 2;      // B DMA per wave per half-tile
  constexpr int NMI = 2, NNJ = 2;
  constexpr int NT = 32;     // K=2048 / 64
  __shared__ __align__(16) _Float16 ls[2 * BUF];

  const int tid = threadIdx.x;
  const int wave = tid >> 6, lane = tid & 63;
  const int wr = wave >> 2, wc = wave & 3;
  const int fm = lane & 15, q = lane >> 4;
  const int bz = blockIdx.x;
  const int m0 = blockIdx.y * BM, n0 = blockIdx.z * BN;

  const int srow = lane >> 3;
  const int schunk = ((lane & 7) ^ (srow & 7)) * 8;
  const int rA0 = m0 + 8 * wave + srow;  // this lane's fixed P-row (A0 half)
  const float2 st0 = rms[bz * 2048 + rA0];
  const float2 st1 = rms[bz * 2048 + rA0 + 64];
  const _Float16* pA0 = S + (long long)bz * 4194304 + (long long)rA0 * 2048 + schunk;
  const _Float16* pA1 = pA0 + 64LL * 2048;
  const _Float16* pB0 = Vt + (long long)bz * 1048576 + (long long)(n0 + 16 * wave + srow) * 2048 + schunk;
  const _Float16* pB1 = pB0 + 128LL * 2048;
  const int dA0 = 8 * wave * 64;          // halfs
  const int dB0 = ASZ + 16 * wave * 64;   // halfs

  const int c0 = (q ^ (fm & 7)) * 8;
  const int c1 = ((q + 4) ^ (fm & 7)) * 8;
  const int arow = wr * (BM / 4) + fm;
  const int brow = wc * (BN / 8) + fm;

  floatx4 acc[2][2][NMI][NNJ] = {};
  half8 afx[2][NMI][2], bfx[2][NNJ][2];

#define PV_EXPW(DST, RA, MM, INV)                                          \
  { half8 pe_;                                                             \
    _Pragma("unroll") for (int e = 0; e < 8; ++e)                          \
      pe_[e] = (_Float16)(__expf((float)(RA)[e] - (MM)) * (INV));          \
    *(half8*)(DST) = pe_; }
#define PV_DMA_B(PTR, OFF)                                                 \
  _Pragma("unroll") for (int s = 0; s < LB; ++s)                           \
    async_load16(PTR + (long long)(8 * s) * 2048, stb + dB0 + (OFF) + s * 512);

  // prologue: stage tile 0 into buf0
  {
    _Float16* stb = ls;
    half8 ra0 = *(const half8*)pA0;
    half8 ra1 = *(const half8*)pA1;
    PV_DMA_B(pB0, 0)
    PV_DMA_B(pB1, BSZ / 2)
    PV_EXPW(&stb[dA0 + lane * 8], ra0, st0.x, st0.y)
    PV_EXPW(&stb[dA0 + ASZ / 2 + lane * 8], ra1, st1.x, st1.y)
    pA0 += 64; pA1 += 64; pB0 += 64; pB1 += 64;
    asm volatile("s_waitcnt vmcnt(0) lgkmcnt(0)" ::: "memory");
  }

  for (int kt = 0; kt < NT; ++kt) {
    const _Float16* cb = ls + (kt & 1) * BUF;
    _Float16* stb = ls + ((kt + 1) & 1) * BUF;
    __builtin_amdgcn_s_barrier();  // publishes tile kt
#pragma unroll
    for (int mh = 0; mh < 2; ++mh)
#pragma unroll
      for (int mi = 0; mi < NMI; ++mi) {
        const int r_ = mh * (BM / 2) + arow + 16 * mi;
        afx[mh][mi][0] = *(const half8*)&cb[r_ * 64 + c0];
        afx[mh][mi][1] = *(const half8*)&cb[r_ * 64 + c1];
      }
#pragma unroll
    for (int nh = 0; nh < 2; ++nh)
#pragma unroll
      for (int nj = 0; nj < NNJ; ++nj) {
        const int r_ = ASZ + (nh * (BN / 2) + brow + 16 * nj) * 64;
        bfx[nh][nj][0] = *(const half8*)&cb[r_ + c0];
        bfx[nh][nj][1] = *(const half8*)&cb[r_ + c1];
      }
    half8 ra0, ra1;
    const bool more = (kt < NT - 1);
    if (more) {
      ra0 = *(const half8*)pA0;
      ra1 = *(const half8*)pA1;
      PV_DMA_B(pB0, 0)
      PV_DMA_B(pB1, BSZ / 2)
      pB0 += 64; pB1 += 64;
    }
    __builtin_amdgcn_s_setprio(1);
#pragma unroll
    for (int kk = 0; kk < 2; ++kk)
#pragma unroll
      for (int mh = 0; mh < 2; ++mh)
#pragma unroll
        for (int mi = 0; mi < NMI; ++mi)
#pragma unroll
          for (int nh = 0; nh < 2; ++nh)
#pragma unroll
            for (int nj = 0; nj < NNJ; ++nj)
              acc[mh][nh][mi][nj] = __builtin_amdgcn_mfma_f32_16x16x32_f16(
                  afx[mh][mi][kk], bfx[nh][nj][kk], acc[mh][nh][mi][nj], 0, 0, 0);
    __builtin_amdgcn_s_setprio(0);
    if (more) {
      PV_EXPW(&stb[dA0 + lane * 8], ra0, st0.x, st0.y)
      PV_EXPW(&stb[dA0 + ASZ / 2 + lane * 8], ra1, st1.x, st1.y)
      pA0 += 64; pA1 += 64;
    }
    asm volatile("s_waitcnt vmcnt(0) lgkmcnt(0)" ::: "memory");
  }
#undef PV_EXPW
#undef PV_DMA_B

  // epilogue
#pragma unroll
  for (int mh = 0; mh < 2; ++mh)
#pragma unroll
    for (int nh = 0; nh < 2; ++nh)
#pragma unroll
      for (int mi = 0; mi < NMI; ++mi)
#pragma unroll
        for (int nj = 0; nj < NNJ; ++nj) {
          const int rr0 = m0 + mh * (BM / 2) + wr * (BM / 4) + 16 * mi + 4 * q;
          const int cc = n0 + nh * (BN / 2) + wc * (BN / 8) + 16 * nj + fm;
#pragma unroll
          for (int t = 0; t < 4; ++t) {
            const int rr = rr0 + t;
            Out[(long long)bz * 1048576 + (long long)rr * 512 + cc] =
                (_Float16)acc[mh][nh][mi][nj][t];
          }
        }
}

extern "C" void kernel_launch(void* const* d_in, const int* in_sizes, int n_in,
                              void* d_out, int out_size, void* d_ws, size_t ws_size,
                              hipStream_t stream) {
  const float* x = (const float*)d_in[0];
  const float* gsc = (const float*)d_in[1];
  const float* gbi = (const float*)d_in[2];
  const float* wq = (const float*)d_in[3];
  const float* bq = (const float*)d_in[4];
  const float* wk = (const float*)d_in[5];
  const float* bk = (const float*)d_in[6];
  const float* wv = (const float*)d_in[7];
  const float* bv = (const float*)d_in[8];
  const float* wo = (const float*)d_in[9];
  const float* bo = (const float*)d_in[10];
  float* out = (float*)d_out;

  // workspace layout (~130 MB total)
  char* ws = (char*)d_ws;
  float* stats = (float*)ws;                 // 512 f32 @ 0
  float* bqk = (float*)(ws + 2048);          // 1024 f32 @ 2 KB
  _Float16* wbf = (_Float16*)(ws + 8192);    // 4 * 512*512 f16 (wq,wk,wv,wo stacked)
  _Float16* ht = wbf + 4 * 262144;           // [b,l,c] f16, 16 MB
  const long long EB = 8LL * 2048 * 512;
  _Float16* qk = ht + EB;       // [b,l,1024] f16 (q||k), 32 MB
  _Float16* vm = qk + 2 * EB;   // [b,c,l] f16, 16 MB
  _Float16* Sb = vm + EB;       // [b,l,l] f16, 64 MB
  _Float16* at = ht;            // attention output aliases ht (ht dead after V-proj)
  float2* rms = (float2*)qk;    // 8*2048 float2 (qk dead after S-GEMM)

  gn_stats<<<256, 256, 0, stream>>>(x, stats);
  gn_apply<<<dim3(32, 8, 8), 256, 0, stream>>>(x, stats, gsc, gbi, ht);
  cast_w<<<4100, 256, 0, stream>>>(wq, wk, wv, wo, bq, bk, wbf, bqk);

  const float scale = 0.044194173824159216f;  // 512^-0.5
  // QK fused: [l, 0:1024] = ht[l,c] . (wq||wk)[o,c]^T + bqk[o]
  gemm2p<256, 256, 1, 1, false><<<dim3(8, 8, 4), 512, 0, stream>>>(
      ht, 1048576LL, 512, wbf, 0LL, 512, qk, 2097152LL, 1024, bqk, nullptr, 0LL, 1.f, 512);
  // V: [o,l] = Wv[o,c] . ht[l,c]^T + bv[o]
  gemm2p<128, 256, 2, 1, false><<<dim3(8, 4, 8), 512, 0, stream>>>(
      wbf + 2 * 262144, 0LL, 512, ht, 1048576LL, 512, vm, 1048576LL, 2048, bv, nullptr, 0LL, 1.f, 512);
  // S: [i,j] = scale * q[i,o] . k[j,o]^T
  gemm2p<256, 256, 0, 1, false><<<dim3(8, 8, 8), 512, 0, stream>>>(
      qk, 2097152LL, 1024, qk + 512, 2097152LL, 1024, Sb, 4194304LL, 2048, nullptr, nullptr, 0LL, scale, 512);
  // per-row softmax stats (qk region is dead now; rms lives there)
  row_stats<<<dim3(2048, 8), 256, 0, stream>>>(Sb, rms);
  // A: [i,c] = softmax(S)[i,j] . vm[c,j]^T  (softmax fused into A-operand staging)
  gemm_pv<<<dim3(8, 16, 2), 512, 0, stream>>>(Sb, rms, vm, at);
  // Out: [o,l] = Wo[o,c] . a[l,c]^T + bo[o] + x[b,o,l]
  gemm2p<128, 256, 2, 0, true><<<dim3(8, 4, 8), 512, 0, stream>>>(
      wbf + 3 * 262144, 0LL, 512, at, 1048576LL, 512, out, 1048576LL, 2048, bo, x, 1048576LL, 1.f, 512);
}